// Round 1
// baseline (2734.386 us; speedup 1.0000x reference)
//
#include <hip/hip_runtime.h>
#include <cstddef>

// Problem constants
#define D_MODEL 768
#define NHEAD   12
#define DHEAD   64
#define RANK    32
#define SEQ     1024
#define BATCH   8
#define BM      8192      // BATCH*SEQ
#define RW_     384
#define RF_     384
#define DFF_    3072

// ---------------------------------------------------------------------------
// Combine per-head low-rank factors: W[d, h*64+k] = sum_r P[h,d,r] * Vw[h,r,k]
// P: (H, D, R), Vw: (H, R, DH), W: (D, H*DH)
// ---------------------------------------------------------------------------
__global__ __launch_bounds__(256) void combine_w_kernel(
    const float* __restrict__ P, const float* __restrict__ Vw,
    float* __restrict__ W) {
  int idx = blockIdx.x * 256 + threadIdx.x;
  if (idx >= D_MODEL * NHEAD * DHEAD) return;
  int d = idx / (NHEAD * DHEAD);
  int c = idx - d * (NHEAD * DHEAD);
  int h = c >> 6, k = c & 63;
  const float* p = P + ((size_t)h * D_MODEL + d) * RANK;
  const float* v = Vw + (size_t)h * RANK * DHEAD + k;
  float s = 0.f;
#pragma unroll
  for (int r = 0; r < RANK; r++) s += p[r] * v[(size_t)r * DHEAD];
  W[(size_t)d * (NHEAD * DHEAD) + c] = s;
}

// ---------------------------------------------------------------------------
// Generic fp32 GEMM: C[M,N] = A[M,K] @ B[K,N] (+bias[col]) (+exact GELU)
// 128x128 tile, BK=16, 256 threads, 8x8 per thread.
// M % 128 == 0, N % 128 == 0, K % 16 == 0 (true for all shapes here).
// ---------------------------------------------------------------------------
__global__ __launch_bounds__(256) void gemm_kernel(
    const float* __restrict__ A, const float* __restrict__ B,
    const float* __restrict__ bias, float* __restrict__ C,
    int M, int N, int K, int gelu) {
  __shared__ __align__(16) float As[16][132];   // transposed: As[k][m]
  __shared__ __align__(16) float Bs[16][132];   // Bs[k][n]
  const int tid = threadIdx.x;
  const int tx = tid & 15;          // 16 col groups
  const int ty = tid >> 4;          // 16 row groups
  const int row0 = blockIdx.y * 128, col0 = blockIdx.x * 128;
  float acc[8][8];
#pragma unroll
  for (int i = 0; i < 8; i++)
#pragma unroll
    for (int j = 0; j < 8; j++) acc[i][j] = 0.f;

  for (int k0 = 0; k0 < K; k0 += 16) {
    {
      int r = tid >> 1, kk = (tid & 1) * 8;
      const float* ap = A + (size_t)(row0 + r) * K + k0 + kk;
      float4 a0 = *(const float4*)ap;
      float4 a1 = *(const float4*)(ap + 4);
      As[kk + 0][r] = a0.x; As[kk + 1][r] = a0.y;
      As[kk + 2][r] = a0.z; As[kk + 3][r] = a0.w;
      As[kk + 4][r] = a1.x; As[kk + 5][r] = a1.y;
      As[kk + 6][r] = a1.z; As[kk + 7][r] = a1.w;
    }
    {
      int kr = tid >> 4, c = (tid & 15) * 8;
      const float* bp = B + (size_t)(k0 + kr) * N + col0 + c;
      *(float4*)&Bs[kr][c]     = *(const float4*)bp;
      *(float4*)&Bs[kr][c + 4] = *(const float4*)(bp + 4);
    }
    __syncthreads();
#pragma unroll
    for (int kk = 0; kk < 16; kk++) {
      float a[8], b[8];
      *(float4*)&a[0] = *(const float4*)&As[kk][ty * 8];
      *(float4*)&a[4] = *(const float4*)&As[kk][ty * 8 + 4];
      *(float4*)&b[0] = *(const float4*)&Bs[kk][tx * 8];
      *(float4*)&b[4] = *(const float4*)&Bs[kk][tx * 8 + 4];
#pragma unroll
      for (int i = 0; i < 8; i++)
#pragma unroll
        for (int j = 0; j < 8; j++) acc[i][j] += a[i] * b[j];
    }
    __syncthreads();
  }

#pragma unroll
  for (int i = 0; i < 8; i++) {
    int r = row0 + ty * 8 + i;
    float* cp = C + (size_t)r * N + col0 + tx * 8;
#pragma unroll
    for (int j = 0; j < 8; j++) {
      float v = acc[i][j];
      if (bias) v += bias[col0 + tx * 8 + j];
      if (gelu) v = 0.5f * v * (1.0f + erff(v * 0.70710678118654752f));
      cp[j] = v;
    }
  }
}

// ---------------------------------------------------------------------------
// Flash attention, fp32. Q/K/V layout: (B*M, H*DH) row-major.
// Block: one (b, h, 32-query tile); 8 key chunks of 128.
// ---------------------------------------------------------------------------
__global__ __launch_bounds__(256) void attn_kernel(
    const float* __restrict__ Q, const float* __restrict__ K,
    const float* __restrict__ V, const float* __restrict__ mask,
    float* __restrict__ O) {
  const int qt = blockIdx.x;
  const int h  = blockIdx.y;
  const int b  = blockIdx.z;
  const int tid = threadIdx.x;

  __shared__ float Qs[32][64];
  __shared__ float Ks[128][65];
  __shared__ float Vs[128][65];
  __shared__ float S[32][129];
  __shared__ float Os[32][64];
  __shared__ float mrow[32], lrow[32], alpha_s[32];
  __shared__ float redm[32][9], reds[32][9];

  const size_t qbase = ((size_t)(b * SEQ + qt * 32)) * D_MODEL + h * DHEAD;
#pragma unroll
  for (int it = 0; it < 8; it++) {
    int idx = tid + it * 256;
    int i = idx >> 6, d = idx & 63;
    Qs[i][d] = Q[qbase + (size_t)i * D_MODEL + d];
    Os[i][d] = 0.f;
  }
  if (tid < 32) { mrow[tid] = -3.0e38f; lrow[tid] = 0.f; alpha_s[tid] = 0.f; }
  __syncthreads();

  for (int n0 = 0; n0 < SEQ; n0 += 128) {
    const size_t kbase = ((size_t)(b * SEQ + n0)) * D_MODEL + h * DHEAD;
#pragma unroll
    for (int it = 0; it < 32; it++) {
      int idx = tid + it * 256;
      int j = idx >> 6, d = idx & 63;
      Ks[j][d] = K[kbase + (size_t)j * D_MODEL + d];
      Vs[j][d] = V[kbase + (size_t)j * D_MODEL + d];
    }
    __syncthreads();

    // ---- scores: thread = 4 rows x 4 cols, d-swizzle kills bank conflicts
    {
      const int jg = tid & 31, ig = tid >> 5;
      const int j0 = jg * 4, i0 = ig * 4;
      float sc[4][4];
#pragma unroll
      for (int ii = 0; ii < 4; ii++)
#pragma unroll
        for (int jj = 0; jj < 4; jj++) sc[ii][jj] = 0.f;
      for (int dd = 0; dd < 64; dd++) {
        int d = (dd + jg) & 63;
        float a[4], bb[4];
#pragma unroll
        for (int ii = 0; ii < 4; ii++) a[ii] = Qs[i0 + ii][d];
#pragma unroll
        for (int jj = 0; jj < 4; jj++) bb[jj] = Ks[j0 + jj][d];
#pragma unroll
        for (int ii = 0; ii < 4; ii++)
#pragma unroll
          for (int jj = 0; jj < 4; jj++) sc[ii][jj] += a[ii] * bb[jj];
      }
#pragma unroll
      for (int jj = 0; jj < 4; jj++) {
        float mk = mask[(size_t)b * SEQ + n0 + j0 + jj];
#pragma unroll
        for (int ii = 0; ii < 4; ii++)
          S[i0 + ii][j0 + jj] = sc[ii][jj] * 0.125f + mk;
      }
    }
    __syncthreads();

    // ---- per-row chunk max (8 threads per row)
    {
      int i = tid >> 3, sub = tid & 7;
      float mx = -3.0e38f;
#pragma unroll
      for (int jj = 0; jj < 16; jj++) mx = fmaxf(mx, S[i][sub * 16 + jj]);
      redm[i][sub] = mx;
    }
    __syncthreads();
    if (tid < 32) {
      float mx = mrow[tid];
#pragma unroll
      for (int s = 0; s < 8; s++) mx = fmaxf(mx, redm[tid][s]);
      float al = __expf(mrow[tid] - mx);   // first chunk: exp(-inf)=0, l starts 0
      mrow[tid] = mx;
      alpha_s[tid] = al;
      lrow[tid] *= al;
    }
    __syncthreads();

    // ---- exponentiate in place + partial row sums
    {
      int i = tid >> 3, sub = tid & 7;
      float m = mrow[i], s = 0.f;
#pragma unroll
      for (int jj = 0; jj < 16; jj++) {
        float p = __expf(S[i][sub * 16 + jj] - m);
        S[i][sub * 16 + jj] = p;
        s += p;
      }
      reds[i][sub] = s;
    }
    __syncthreads();
    if (tid < 32) {
      float s = 0.f;
#pragma unroll
      for (int q = 0; q < 8; q++) s += reds[tid][q];
      lrow[tid] += s;
    }
    // ---- O = O*alpha + P @ V  (thread = 4 rows x 2 dims, j-swizzled)
    {
      int rg = tid >> 5, dg = tid & 31;
      float o[4][2];
#pragma unroll
      for (int rr = 0; rr < 4; rr++) {
        float al = alpha_s[rg * 4 + rr];
        o[rr][0] = Os[rg * 4 + rr][dg * 2 + 0] * al;
        o[rr][1] = Os[rg * 4 + rr][dg * 2 + 1] * al;
      }
      for (int jj = 0; jj < 128; jj++) {
        int j = (jj + dg) & 127;
        float v0 = Vs[j][dg * 2 + 0], v1 = Vs[j][dg * 2 + 1];
#pragma unroll
        for (int rr = 0; rr < 4; rr++) {
          float p = S[rg * 4 + rr][j];
          o[rr][0] += p * v0;
          o[rr][1] += p * v1;
        }
      }
#pragma unroll
      for (int rr = 0; rr < 4; rr++) {
        Os[rg * 4 + rr][dg * 2 + 0] = o[rr][0];
        Os[rg * 4 + rr][dg * 2 + 1] = o[rr][1];
      }
    }
    __syncthreads();
  }

  // ---- normalize + write out (B*M, H*DH)
  {
    int rg = tid >> 5, dg = tid & 31;
#pragma unroll
    for (int rr = 0; rr < 4; rr++) {
      int i = rg * 4 + rr;
      float inv = 1.f / lrow[i];
      size_t ob = ((size_t)(b * SEQ + qt * 32 + i)) * D_MODEL + h * DHEAD + dg * 2;
      O[ob + 0] = Os[i][dg * 2 + 0] * inv;
      O[ob + 1] = Os[i][dg * 2 + 1] * inv;
    }
  }
}

// ---------------------------------------------------------------------------
// out[row] = LayerNorm(Ain[row] + Bin[row]) * g + bt   (768 cols, eps=1e-12)
// one block per row, 256 threads x 3 cols each
// ---------------------------------------------------------------------------
__global__ __launch_bounds__(256) void add_ln_kernel(
    const float* __restrict__ Ain, const float* __restrict__ Bin,
    const float* __restrict__ g, const float* __restrict__ bt,
    float* __restrict__ out) {
  const int row = blockIdx.x, tid = threadIdx.x;
  __shared__ float red[4];
  float v[3];
  float s = 0.f;
#pragma unroll
  for (int u = 0; u < 3; u++) {
    int c = tid + u * 256;
    v[u] = Ain[(size_t)row * 768 + c] + Bin[(size_t)row * 768 + c];
    s += v[u];
  }
#pragma unroll
  for (int off = 32; off > 0; off >>= 1) s += __shfl_down(s, off);
  if ((tid & 63) == 0) red[tid >> 6] = s;
  __syncthreads();
  float mu = (red[0] + red[1] + red[2] + red[3]) * (1.f / 768.f);
  float s2 = 0.f;
#pragma unroll
  for (int u = 0; u < 3; u++) { float d = v[u] - mu; s2 += d * d; }
#pragma unroll
  for (int off = 32; off > 0; off >>= 1) s2 += __shfl_down(s2, off);
  __syncthreads();
  if ((tid & 63) == 0) red[tid >> 6] = s2;
  __syncthreads();
  float var = (red[0] + red[1] + red[2] + red[3]) * (1.f / 768.f);
  float inv = rsqrtf(var + 1e-12f);
#pragma unroll
  for (int u = 0; u < 3; u++) {
    int c = tid + u * 256;
    out[(size_t)row * 768 + c] = g[c] * (v[u] - mu) * inv + bt[c];
  }
}

// ---------------------------------------------------------------------------
extern "C" void kernel_launch(void* const* d_in, const int* in_sizes, int n_in,
                              void* d_out, int out_size, void* d_ws, size_t ws_size,
                              hipStream_t stream) {
  const float* x    = (const float*)d_in[0];
  const float* mask = (const float*)d_in[1];
  const float* Pq   = (const float*)d_in[2];
  const float* Vq   = (const float*)d_in[3];
  const float* bq   = (const float*)d_in[4];
  const float* Pk   = (const float*)d_in[5];
  const float* Vk   = (const float*)d_in[6];
  const float* bk   = (const float*)d_in[7];
  const float* Pv   = (const float*)d_in[8];
  const float* Vv   = (const float*)d_in[9];
  const float* bv   = (const float*)d_in[10];
  const float* Uo   = (const float*)d_in[11];
  const float* Vo   = (const float*)d_in[12];
  const float* bo   = (const float*)d_in[13];
  const float* U1   = (const float*)d_in[14];
  const float* V1   = (const float*)d_in[15];
  const float* b1   = (const float*)d_in[16];
  const float* U2   = (const float*)d_in[17];
  const float* V2   = (const float*)d_in[18];
  const float* b2   = (const float*)d_in[19];
  const float* g1   = (const float*)d_in[20];
  const float* be1  = (const float*)d_in[21];
  const float* g2   = (const float*)d_in[22];
  const float* be2  = (const float*)d_in[23];

  // Workspace layout (floats). Peak = 45,809,664 floats = 183.2 MB.
  float* ws   = (float*)d_ws;
  float* Wq   = ws;
  float* Wk   = Wq + 589824;
  float* Wv   = Wk + 589824;
  float* Qb   = Wv + 589824;          // 6,291,456 each
  float* Kb   = Qb + 6291456;
  float* Vb   = Kb + 6291456;
  float* attn = Vb + 6291456;
  float* t1   = attn + 6291456;       // 3,145,728
  float* y1   = t1 + 3145728;         // 6,291,456
  float* x1   = y1 + 6291456;         // 6,291,456
  float* mid  = x1 + 6291456;         // 3,145,728
  float* hidden = Qb;                 // reuse Q/K/V/attn region: 25,165,824 floats
  float* t2   = t1;                   // reuse (t1 dead after y1)
  float* y2   = y1;                   // reuse (y1 dead after LN1)
  float* outp = (float*)d_out;

  // 1) combine low-rank QKV weights: W = P @ V per head -> (768, 768)
  combine_w_kernel<<<2304, 256, 0, stream>>>(Pq, Vq, Wq);
  combine_w_kernel<<<2304, 256, 0, stream>>>(Pk, Vk, Wk);
  combine_w_kernel<<<2304, 256, 0, stream>>>(Pv, Vv, Wv);

  // 2) Q/K/V = x @ W + bias   (bias flat (H*DH) == column index)
  gemm_kernel<<<dim3(6, 64), 256, 0, stream>>>(x, Wq, bq, Qb, BM, 768, 768, 0);
  gemm_kernel<<<dim3(6, 64), 256, 0, stream>>>(x, Wk, bk, Kb, BM, 768, 768, 0);
  gemm_kernel<<<dim3(6, 64), 256, 0, stream>>>(x, Wv, bv, Vb, BM, 768, 768, 0);

  // 3) attention -> (B*M, H*DH)
  attn_kernel<<<dim3(32, 12, 8), 256, 0, stream>>>(Qb, Kb, Vb, mask, attn);

  // 4) attn out projection (low rank) + residual + LN1
  gemm_kernel<<<dim3(3, 64), 256, 0, stream>>>(attn, Uo, nullptr, t1, BM, 384, 768, 0);
  gemm_kernel<<<dim3(6, 64), 256, 0, stream>>>(t1, Vo, bo, y1, BM, 768, 384, 0);
  add_ln_kernel<<<8192, 256, 0, stream>>>(x, y1, g1, be1, x1);

  // 5) FFN (low rank) with exact GELU
  gemm_kernel<<<dim3(3, 64), 256, 0, stream>>>(x1, U1, nullptr, mid, BM, 384, 768, 0);
  gemm_kernel<<<dim3(24, 64), 256, 0, stream>>>(mid, V1, b1, hidden, BM, 3072, 384, 1);
  gemm_kernel<<<dim3(3, 64), 256, 0, stream>>>(hidden, U2, nullptr, t2, BM, 384, 3072, 0);
  gemm_kernel<<<dim3(6, 64), 256, 0, stream>>>(t2, V2, b2, y2, BM, 768, 384, 0);

  // 6) residual + LN2 -> output
  add_ln_kernel<<<8192, 256, 0, stream>>>(x1, y2, g2, be2, outp);
}

// Round 2
// 1283.470 us; speedup vs baseline: 2.1305x; 2.1305x over previous
//
#include <hip/hip_runtime.h>
#include <cstddef>

// Problem constants
#define D_MODEL 768
#define NHEAD   12
#define DHEAD   64
#define RANK    32
#define SEQ     1024
#define BATCH   8
#define BM      8192      // BATCH*SEQ

typedef __attribute__((ext_vector_type(8))) short short8;
typedef __attribute__((ext_vector_type(4))) float floatx4;

__device__ inline ushort f2b(float f) {           // fp32 -> bf16 RNE
  union { float f; unsigned u; } v; v.f = f;
  unsigned r = v.u + 0x7fffu + ((v.u >> 16) & 1u);
  return (ushort)(r >> 16);
}
__device__ inline float b2f(ushort h) {
  union { unsigned u; float f; } v; v.u = ((unsigned)h) << 16;
  return v.f;
}

// ---------------------------------------------------------------------------
// fp32 -> bf16 flat convert (n divisible by 4)
// ---------------------------------------------------------------------------
__global__ __launch_bounds__(256) void f2b_kernel(
    const float* __restrict__ in, ushort* __restrict__ out, int n) {
  int i = (blockIdx.x * 256 + threadIdx.x) * 4;
  if (i >= n) return;
  float4 v = *(const float4*)(in + i);
  ushort4 o;
  o.x = f2b(v.x); o.y = f2b(v.y); o.z = f2b(v.z); o.w = f2b(v.w);
  *(ushort4*)(out + i) = o;
}

// ---------------------------------------------------------------------------
// Combine per-head low-rank factors, TRANSPOSED bf16 output:
// Wt[c=h*64+k][d] = sum_r P[h,d,r] * Vw[h,r,k]    (N=768 rows, K=768 cols)
// ---------------------------------------------------------------------------
__global__ __launch_bounds__(256) void combine_w_kernel(
    const float* __restrict__ P, const float* __restrict__ Vw,
    ushort* __restrict__ Wt) {
  int idx = blockIdx.x * 256 + threadIdx.x;
  if (idx >= D_MODEL * NHEAD * DHEAD) return;
  int c = idx / D_MODEL;            // output row (h*64+k)
  int d = idx - c * D_MODEL;        // output col
  int h = c >> 6, k = c & 63;
  const float* p = P + ((size_t)h * D_MODEL + d) * RANK;
  const float* v = Vw + (size_t)h * RANK * DHEAD + k;
  float s = 0.f;
#pragma unroll
  for (int r = 0; r < RANK; r++) s += p[r] * v[(size_t)r * DHEAD];
  Wt[(size_t)c * D_MODEL + d] = f2b(s);
}

// ---------------------------------------------------------------------------
// Transpose + convert: in (R,C) fp32 -> out (C,R) bf16.  R,C % 32 == 0.
// grid (C/32, R/32), 256 threads (32x8)
// ---------------------------------------------------------------------------
__global__ __launch_bounds__(256) void transpose_b_kernel(
    const float* __restrict__ in, ushort* __restrict__ out, int R, int C) {
  __shared__ float t[32][33];
  int c0 = blockIdx.x * 32, r0 = blockIdx.y * 32;
  int lx = threadIdx.x & 31, ly = threadIdx.x >> 5;
#pragma unroll
  for (int i = 0; i < 32; i += 8)
    t[ly + i][lx] = in[(size_t)(r0 + ly + i) * C + c0 + lx];
  __syncthreads();
#pragma unroll
  for (int i = 0; i < 32; i += 8)
    out[(size_t)(c0 + ly + i) * R + r0 + lx] = f2b(t[lx][ly + i]);
}

// ---------------------------------------------------------------------------
// bf16 MFMA GEMM: C[M,N] = A[M,K] @ Bt[N,K]^T (+bias) (+gelu)
// 128x128 tile, BK=32, 256 threads (4 waves, each 64x64 via 4x4 MFMA tiles).
// A row-major bf16, Bt row-major bf16 (i.e. B transposed). fp32 accumulate.
// M,N,K multiples of 128/128/32.
// ---------------------------------------------------------------------------
template <int OUTBF16, int BIAS, int GELU>
__global__ __launch_bounds__(256) void gemm_mfma_kernel(
    const ushort* __restrict__ A, const ushort* __restrict__ Bt,
    const float* __restrict__ bias, void* __restrict__ C,
    int M, int N, int K) {
  __shared__ __align__(16) ushort Als[128 * 32];
  __shared__ __align__(16) ushort Bls[128 * 32];
  const int tid  = threadIdx.x;
  const int lane = tid & 63;
  const int quad = lane >> 4, l16 = lane & 15;
  const int wu   = __builtin_amdgcn_readfirstlane(tid >> 6);
  const int wrow = (wu >> 1) * 64, wcol = (wu & 1) * 64;
  const int row0 = blockIdx.y * 128, col0 = blockIdx.x * 128;

  floatx4 acc[4][4] = {};

  for (int k0 = 0; k0 < K; k0 += 32) {
    __syncthreads();
#pragma unroll
    for (int is = 0; is < 2; is++) {
      int c = is * 256 + wu * 64 + lane;        // 16B chunk id
      int m = c >> 2, kk = (c & 3) << 3;
      const ushort* ga = A + (size_t)(row0 + m) * K + (k0 + kk);
      ushort* la = Als + (size_t)(is * 256 + wu * 64) * 8;   // wave-uniform base
      __builtin_amdgcn_global_load_lds(
          (const __attribute__((address_space(1))) void*)ga,
          (__attribute__((address_space(3))) void*)la, 16, 0, 0);
      const ushort* gb = Bt + (size_t)(col0 + m) * K + (k0 + kk);  // n == m pattern
      ushort* lb = Bls + (size_t)(is * 256 + wu * 64) * 8;
      __builtin_amdgcn_global_load_lds(
          (const __attribute__((address_space(1))) void*)gb,
          (__attribute__((address_space(3))) void*)lb, 16, 0, 0);
    }
    __syncthreads();

    short8 af[4], bf[4];
#pragma unroll
    for (int mt = 0; mt < 4; mt++)
      af[mt] = *(const short8*)(Als + ((wrow + mt * 16 + l16) * 32 + quad * 8));
#pragma unroll
    for (int nt = 0; nt < 4; nt++)
      bf[nt] = *(const short8*)(Bls + ((wcol + nt * 16 + l16) * 32 + quad * 8));
#pragma unroll
    for (int mt = 0; mt < 4; mt++)
#pragma unroll
      for (int nt = 0; nt < 4; nt++)
        acc[mt][nt] = __builtin_amdgcn_mfma_f32_16x16x32_bf16(
            af[mt], bf[nt], acc[mt][nt], 0, 0, 0);
  }

  // Epilogue: C/D layout col = lane&15, row = quad*4 + reg
#pragma unroll
  for (int mt = 0; mt < 4; mt++) {
#pragma unroll
    for (int nt = 0; nt < 4; nt++) {
      int colg = col0 + wcol + nt * 16 + l16;
      float bv_ = BIAS ? bias[colg] : 0.f;
#pragma unroll
      for (int r = 0; r < 4; r++) {
        int rowg = row0 + wrow + mt * 16 + quad * 4 + r;
        float v = acc[mt][nt][r] + bv_;
        if (GELU) v = 0.5f * v * (1.0f + erff(v * 0.70710678118654752f));
        if (OUTBF16)
          ((ushort*)C)[(size_t)rowg * N + colg] = f2b(v);
        else
          ((float*)C)[(size_t)rowg * N + colg] = v;
      }
    }
  }
}

// ---------------------------------------------------------------------------
// Flash attention, fp32 in / bf16 out. Q/K/V: (B*M, H*DH) fp32 row-major.
// Block = (32-query tile, h, b); key chunks of 64; O-acc in registers.
// LDS ~52.6 KB -> 3 blocks/CU.
// ---------------------------------------------------------------------------
__global__ __launch_bounds__(256) void attn_kernel(
    const float* __restrict__ Q, const float* __restrict__ K,
    const float* __restrict__ V, const float* __restrict__ mask,
    ushort* __restrict__ O) {
  const int qt = blockIdx.x, h = blockIdx.y, b = blockIdx.z;
  const int tid = threadIdx.x;

  __shared__ float Qs[32][65];
  __shared__ float Ks[64][65];
  __shared__ float Vs[64][65];
  __shared__ float S[32][65];
  __shared__ float mrow[32], lrow[32], alpha_s[32];
  __shared__ float redm[32][9], reds[32][9];

  const size_t qbase = ((size_t)(b * SEQ + qt * 32)) * D_MODEL + h * DHEAD;
#pragma unroll
  for (int it = 0; it < 8; it++) {
    int idx = tid + it * 256;
    int i = idx >> 6, d = idx & 63;
    Qs[i][d] = Q[qbase + (size_t)i * D_MODEL + d];
  }
  if (tid < 32) { mrow[tid] = -3.0e38f; lrow[tid] = 0.f; }

  const int rg = tid >> 5, dg = tid & 31;    // PV mapping: 4 rows x 2 dims
  float o[4][2] = {};
  __syncthreads();

  for (int n0 = 0; n0 < SEQ; n0 += 64) {
    const size_t kbase = ((size_t)(b * SEQ + n0)) * D_MODEL + h * DHEAD;
#pragma unroll
    for (int it = 0; it < 16; it++) {
      int idx = tid + it * 256;
      int j = idx >> 6, d = idx & 63;
      Ks[j][d] = K[kbase + (size_t)j * D_MODEL + d];
      Vs[j][d] = V[kbase + (size_t)j * D_MODEL + d];
    }
    __syncthreads();

    // scores: thread = 2 rows x 4 cols, d-swizzled
    {
      const int jg = tid & 15, ig = tid >> 4;
      const int j0 = jg * 4, i0 = ig * 2;
      float sc[2][4] = {};
      for (int dd = 0; dd < 64; dd++) {
        int d = (dd + jg) & 63;
        float a0 = Qs[i0][d], a1 = Qs[i0 + 1][d];
#pragma unroll
        for (int jj = 0; jj < 4; jj++) {
          float bb = Ks[j0 + jj][d];
          sc[0][jj] += a0 * bb;
          sc[1][jj] += a1 * bb;
        }
      }
#pragma unroll
      for (int jj = 0; jj < 4; jj++) {
        float mk = mask[(size_t)b * SEQ + n0 + j0 + jj];
        S[i0][j0 + jj]     = sc[0][jj] * 0.125f + mk;
        S[i0 + 1][j0 + jj] = sc[1][jj] * 0.125f + mk;
      }
    }
    __syncthreads();

    // per-row chunk max (8 threads/row x 8 cols)
    {
      int i = tid >> 3, sub = tid & 7;
      float mx = -3.0e38f;
#pragma unroll
      for (int jj = 0; jj < 8; jj++) mx = fmaxf(mx, S[i][sub * 8 + jj]);
      redm[i][sub] = mx;
    }
    __syncthreads();
    if (tid < 32) {
      float mx = mrow[tid];
#pragma unroll
      for (int s = 0; s < 8; s++) mx = fmaxf(mx, redm[tid][s]);
      alpha_s[tid] = __expf(mrow[tid] - mx);   // first chunk: exp(-inf)=0
      mrow[tid] = mx;
      lrow[tid] *= alpha_s[tid];
    }
    __syncthreads();

    // exponentiate in place + partial sums
    {
      int i = tid >> 3, sub = tid & 7;
      float m = mrow[i], s = 0.f;
#pragma unroll
      for (int jj = 0; jj < 8; jj++) {
        float p = __expf(S[i][sub * 8 + jj] - m);
        S[i][sub * 8 + jj] = p;
        s += p;
      }
      reds[i][sub] = s;
    }
    __syncthreads();
    if (tid < 32) {
      float s = 0.f;
#pragma unroll
      for (int q2 = 0; q2 < 8; q2++) s += reds[tid][q2];
      lrow[tid] += s;
    }
    // O = O*alpha + P @ V  (registers, j-swizzled)
    {
#pragma unroll
      for (int rr = 0; rr < 4; rr++) {
        float al = alpha_s[rg * 4 + rr];
        o[rr][0] *= al; o[rr][1] *= al;
      }
      for (int jj = 0; jj < 64; jj++) {
        int j = (jj + dg) & 63;
        float v0 = Vs[j][dg * 2 + 0], v1 = Vs[j][dg * 2 + 1];
#pragma unroll
        for (int rr = 0; rr < 4; rr++) {
          float p = S[rg * 4 + rr][j];
          o[rr][0] += p * v0;
          o[rr][1] += p * v1;
        }
      }
    }
    __syncthreads();
  }

  // normalize + write bf16 (B*M, H*DH)
#pragma unroll
  for (int rr = 0; rr < 4; rr++) {
    int i = rg * 4 + rr;
    float inv = 1.f / lrow[i];
    size_t ob = ((size_t)(b * SEQ + qt * 32 + i)) * D_MODEL + h * DHEAD + dg * 2;
    O[ob + 0] = f2b(o[rr][0] * inv);
    O[ob + 1] = f2b(o[rr][1] * inv);
  }
}

// ---------------------------------------------------------------------------
// out = LayerNorm(Ain + Bin)*g + bt ; optional bf16 copy outb. 768 cols.
// ---------------------------------------------------------------------------
__global__ __launch_bounds__(256) void add_ln_kernel(
    const float* __restrict__ Ain, const float* __restrict__ Bin,
    const float* __restrict__ g, const float* __restrict__ bt,
    float* __restrict__ out, ushort* __restrict__ outb) {
  const int row = blockIdx.x, tid = threadIdx.x;
  __shared__ float red[4];
  float v[3];
  float s = 0.f;
#pragma unroll
  for (int u = 0; u < 3; u++) {
    int c = tid + u * 256;
    v[u] = Ain[(size_t)row * 768 + c] + Bin[(size_t)row * 768 + c];
    s += v[u];
  }
#pragma unroll
  for (int off = 32; off > 0; off >>= 1) s += __shfl_down(s, off);
  if ((tid & 63) == 0) red[tid >> 6] = s;
  __syncthreads();
  float mu = (red[0] + red[1] + red[2] + red[3]) * (1.f / 768.f);
  float s2 = 0.f;
#pragma unroll
  for (int u = 0; u < 3; u++) { float d = v[u] - mu; s2 += d * d; }
#pragma unroll
  for (int off = 32; off > 0; off >>= 1) s2 += __shfl_down(s2, off);
  __syncthreads();
  if ((tid & 63) == 0) red[tid >> 6] = s2;
  __syncthreads();
  float var = (red[0] + red[1] + red[2] + red[3]) * (1.f / 768.f);
  float inv = rsqrtf(var + 1e-12f);
#pragma unroll
  for (int u = 0; u < 3; u++) {
    int c = tid + u * 256;
    float r = g[c] * (v[u] - mu) * inv + bt[c];
    out[(size_t)row * 768 + c] = r;
    if (outb) outb[(size_t)row * 768 + c] = f2b(r);
  }
}

// ---------------------------------------------------------------------------
extern "C" void kernel_launch(void* const* d_in, const int* in_sizes, int n_in,
                              void* d_out, int out_size, void* d_ws, size_t ws_size,
                              hipStream_t stream) {
  const float* x    = (const float*)d_in[0];
  const float* mask = (const float*)d_in[1];
  const float* Pq   = (const float*)d_in[2];
  const float* Vq   = (const float*)d_in[3];
  const float* bq   = (const float*)d_in[4];
  const float* Pk   = (const float*)d_in[5];
  const float* Vk   = (const float*)d_in[6];
  const float* bk   = (const float*)d_in[7];
  const float* Pv   = (const float*)d_in[8];
  const float* Vv   = (const float*)d_in[9];
  const float* bv   = (const float*)d_in[10];
  const float* Uo   = (const float*)d_in[11];
  const float* Vo   = (const float*)d_in[12];
  const float* bo   = (const float*)d_in[13];
  const float* U1   = (const float*)d_in[14];
  const float* V1   = (const float*)d_in[15];
  const float* b1   = (const float*)d_in[16];
  const float* U2   = (const float*)d_in[17];
  const float* V2   = (const float*)d_in[18];
  const float* b2   = (const float*)d_in[19];
  const float* g1   = (const float*)d_in[20];
  const float* be1  = (const float*)d_in[21];
  const float* g2   = (const float*)d_in[22];
  const float* be2  = (const float*)d_in[23];

  // --- workspace carve (bytes, 256-aligned) ---
  char* w = (char*)d_ws;
  auto alloc = [&](size_t bytes) -> char* {
    char* p = w; w += (bytes + 255) & ~(size_t)255; return p;
  };
  ushort* xb    = (ushort*)alloc((size_t)BM * 768 * 2);
  ushort* Wqt   = (ushort*)alloc(768 * 768 * 2);
  ushort* Wkt   = (ushort*)alloc(768 * 768 * 2);
  ushort* Wvt   = (ushort*)alloc(768 * 768 * 2);
  ushort* Uot   = (ushort*)alloc(384 * 768 * 2);
  ushort* Vot   = (ushort*)alloc(768 * 384 * 2);
  ushort* U1t   = (ushort*)alloc(384 * 768 * 2);
  ushort* V1t   = (ushort*)alloc((size_t)3072 * 384 * 2);
  ushort* U2t   = (ushort*)alloc((size_t)384 * 3072 * 2);
  ushort* V2t   = (ushort*)alloc(768 * 384 * 2);
  float*  Qf    = (float*)alloc((size_t)BM * 768 * 4);
  float*  Kf    = (float*)alloc((size_t)BM * 768 * 4);
  float*  Vf    = (float*)alloc((size_t)BM * 768 * 4);
  ushort* attnb = (ushort*)alloc((size_t)BM * 768 * 2);
  ushort* t1b   = (ushort*)alloc((size_t)BM * 384 * 2);
  float*  y1    = (float*)alloc((size_t)BM * 768 * 4);
  float*  x1    = (float*)alloc((size_t)BM * 768 * 4);
  ushort* x1b   = (ushort*)alloc((size_t)BM * 768 * 2);
  // aliases (dead-buffer reuse)
  ushort* midb    = t1b;            // t1b dead after y1 GEMM
  ushort* hiddenb = (ushort*)Qf;    // Qf+Kf region dead after attention
  ushort* t2b     = attnb;          // attnb dead after t1 GEMM
  float*  y2      = y1;             // y1 dead after LN1
  float*  outp    = (float*)d_out;

  // 1) conversions / weight prep
  f2b_kernel<<<(BM * 768) / 1024, 256, 0, stream>>>(x, xb, BM * 768);
  combine_w_kernel<<<2304, 256, 0, stream>>>(Pq, Vq, Wqt);
  combine_w_kernel<<<2304, 256, 0, stream>>>(Pk, Vk, Wkt);
  combine_w_kernel<<<2304, 256, 0, stream>>>(Pv, Vv, Wvt);
  transpose_b_kernel<<<dim3(12, 24), 256, 0, stream>>>(Uo, Uot, 768, 384);
  transpose_b_kernel<<<dim3(24, 12), 256, 0, stream>>>(Vo, Vot, 384, 768);
  transpose_b_kernel<<<dim3(12, 24), 256, 0, stream>>>(U1, U1t, 768, 384);
  transpose_b_kernel<<<dim3(96, 12), 256, 0, stream>>>(V1, V1t, 384, 3072);
  transpose_b_kernel<<<dim3(12, 96), 256, 0, stream>>>(U2, U2t, 3072, 384);
  transpose_b_kernel<<<dim3(24, 12), 256, 0, stream>>>(V2, V2t, 384, 768);

  // 2) Q/K/V = x @ W + bias  (fp32 out for fp32 attention)
  gemm_mfma_kernel<0, 1, 0><<<dim3(6, 64), 256, 0, stream>>>(xb, Wqt, bq, Qf, BM, 768, 768);
  gemm_mfma_kernel<0, 1, 0><<<dim3(6, 64), 256, 0, stream>>>(xb, Wkt, bk, Kf, BM, 768, 768);
  gemm_mfma_kernel<0, 1, 0><<<dim3(6, 64), 256, 0, stream>>>(xb, Wvt, bv, Vf, BM, 768, 768);

  // 3) attention -> bf16 (B*M, 768)
  attn_kernel<<<dim3(32, 12, 8), 256, 0, stream>>>(Qf, Kf, Vf, mask, attnb);

  // 4) out-projection (low rank) + residual + LN1
  gemm_mfma_kernel<1, 0, 0><<<dim3(3, 64), 256, 0, stream>>>(attnb, Uot, nullptr, t1b, BM, 384, 768);
  gemm_mfma_kernel<0, 1, 0><<<dim3(6, 64), 256, 0, stream>>>(t1b, Vot, bo, y1, BM, 768, 384);
  add_ln_kernel<<<BM, 256, 0, stream>>>(x, y1, g1, be1, x1, x1b);

  // 5) FFN (low rank) with exact GELU
  gemm_mfma_kernel<1, 0, 0><<<dim3(3, 64), 256, 0, stream>>>(x1b, U1t, nullptr, midb, BM, 384, 768);
  gemm_mfma_kernel<1, 1, 1><<<dim3(24, 64), 256, 0, stream>>>(midb, V1t, b1, hiddenb, BM, 3072, 384);
  gemm_mfma_kernel<1, 0, 0><<<dim3(3, 64), 256, 0, stream>>>(hiddenb, U2t, nullptr, t2b, BM, 384, 3072);
  gemm_mfma_kernel<0, 1, 0><<<dim3(6, 64), 256, 0, stream>>>(t2b, V2t, b2, y2, BM, 768, 384);

  // 6) residual + LN2 -> output (fp32)
  add_ln_kernel<<<BM, 256, 0, stream>>>(x1, y2, g2, be2, outp, nullptr);
}

// Round 3
// 554.881 us; speedup vs baseline: 4.9279x; 2.3131x over previous
//
#include <hip/hip_runtime.h>
#include <cstddef>

// Problem constants
#define D_MODEL 768
#define NHEAD   12
#define DHEAD   64
#define RANK    32
#define SEQ     1024
#define BATCH   8
#define BM      8192      // BATCH*SEQ

typedef __attribute__((ext_vector_type(8))) short short8;
typedef __attribute__((ext_vector_type(4))) float floatx4;

__device__ inline ushort f2b(float f) {           // fp32 -> bf16 RNE
  union { float f; unsigned u; } v; v.f = f;
  unsigned r = v.u + 0x7fffu + ((v.u >> 16) & 1u);
  return (ushort)(r >> 16);
}

// ---------------------------------------------------------------------------
// fp32 -> bf16 flat convert (n divisible by 4)
// ---------------------------------------------------------------------------
__global__ __launch_bounds__(256) void f2b_kernel(
    const float* __restrict__ in, ushort* __restrict__ out, int n) {
  int i = (blockIdx.x * 256 + threadIdx.x) * 4;
  if (i >= n) return;
  float4 v = *(const float4*)(in + i);
  ushort4 o;
  o.x = f2b(v.x); o.y = f2b(v.y); o.z = f2b(v.z); o.w = f2b(v.w);
  *(ushort4*)(out + i) = o;
}

// ---------------------------------------------------------------------------
// Combine per-head low-rank factors, TRANSPOSED bf16 output:
// Wt[c=h*64+k][d] = sum_r P[h,d,r] * Vw[h,r,k]
// ---------------------------------------------------------------------------
__global__ __launch_bounds__(256) void combine_w_kernel(
    const float* __restrict__ P, const float* __restrict__ Vw,
    ushort* __restrict__ Wt) {
  int idx = blockIdx.x * 256 + threadIdx.x;
  if (idx >= D_MODEL * NHEAD * DHEAD) return;
  int c = idx / D_MODEL;            // output row (h*64+k)
  int d = idx - c * D_MODEL;        // output col
  int h = c >> 6, k = c & 63;
  const float* p = P + ((size_t)h * D_MODEL + d) * RANK;
  const float* v = Vw + (size_t)h * RANK * DHEAD + k;
  float s = 0.f;
#pragma unroll
  for (int r = 0; r < RANK; r++) s += p[r] * v[(size_t)r * DHEAD];
  Wt[(size_t)c * D_MODEL + d] = f2b(s);
}

// ---------------------------------------------------------------------------
// Transpose + convert: in (R,C) fp32 -> out (C,R) bf16.  R,C % 32 == 0.
// ---------------------------------------------------------------------------
__global__ __launch_bounds__(256) void transpose_b_kernel(
    const float* __restrict__ in, ushort* __restrict__ out, int R, int C) {
  __shared__ float t[32][33];
  int c0 = blockIdx.x * 32, r0 = blockIdx.y * 32;
  int lx = threadIdx.x & 31, ly = threadIdx.x >> 5;
#pragma unroll
  for (int i = 0; i < 32; i += 8)
    t[ly + i][lx] = in[(size_t)(r0 + ly + i) * C + c0 + lx];
  __syncthreads();
#pragma unroll
  for (int i = 0; i < 32; i += 8)
    out[(size_t)(c0 + ly + i) * R + r0 + lx] = f2b(t[lx][ly + i]);
}

// ---------------------------------------------------------------------------
// bf16 MFMA GEMM: C = A[M,K] @ Bt[N,K]^T (+bias) (+gelu)
// OUTMODE: 0 = fp32 (M,N); 1 = bf16 (M,N); 2 = bf16 transposed (N,M)
// 128x128 tile, BK=32, 256 threads (4 waves, 64x64 each via 4x4 MFMA tiles).
// ---------------------------------------------------------------------------
template <int OUTMODE, int BIAS, int GELU>
__global__ __launch_bounds__(256) void gemm_mfma_kernel(
    const ushort* __restrict__ A, const ushort* __restrict__ Bt,
    const float* __restrict__ bias, void* __restrict__ C,
    int M, int N, int K) {
  __shared__ __align__(16) ushort Als[128 * 32];
  __shared__ __align__(16) ushort Bls[128 * 32];
  const int tid  = threadIdx.x;
  const int lane = tid & 63;
  const int quad = lane >> 4, l16 = lane & 15;
  const int wu   = __builtin_amdgcn_readfirstlane(tid >> 6);
  const int wrow = (wu >> 1) * 64, wcol = (wu & 1) * 64;
  const int row0 = blockIdx.y * 128, col0 = blockIdx.x * 128;

  floatx4 acc[4][4] = {};

  for (int k0 = 0; k0 < K; k0 += 32) {
    __syncthreads();
#pragma unroll
    for (int is = 0; is < 2; is++) {
      int c = is * 256 + wu * 64 + lane;        // 16B chunk id
      int m = c >> 2, kk = (c & 3) << 3;
      const ushort* ga = A + (size_t)(row0 + m) * K + (k0 + kk);
      ushort* la = Als + (size_t)(is * 256 + wu * 64) * 8;   // wave-uniform base
      __builtin_amdgcn_global_load_lds(
          (const __attribute__((address_space(1))) void*)ga,
          (__attribute__((address_space(3))) void*)la, 16, 0, 0);
      const ushort* gb = Bt + (size_t)(col0 + m) * K + (k0 + kk);
      ushort* lb = Bls + (size_t)(is * 256 + wu * 64) * 8;
      __builtin_amdgcn_global_load_lds(
          (const __attribute__((address_space(1))) void*)gb,
          (__attribute__((address_space(3))) void*)lb, 16, 0, 0);
    }
    __syncthreads();

    short8 af[4], bf[4];
#pragma unroll
    for (int mt = 0; mt < 4; mt++)
      af[mt] = *(const short8*)(Als + ((wrow + mt * 16 + l16) * 32 + quad * 8));
#pragma unroll
    for (int nt = 0; nt < 4; nt++)
      bf[nt] = *(const short8*)(Bls + ((wcol + nt * 16 + l16) * 32 + quad * 8));
#pragma unroll
    for (int mt = 0; mt < 4; mt++)
#pragma unroll
      for (int nt = 0; nt < 4; nt++)
        acc[mt][nt] = __builtin_amdgcn_mfma_f32_16x16x32_bf16(
            af[mt], bf[nt], acc[mt][nt], 0, 0, 0);
  }

  // Epilogue: C/D layout col = lane&15, row = quad*4 + reg
#pragma unroll
  for (int mt = 0; mt < 4; mt++) {
#pragma unroll
    for (int nt = 0; nt < 4; nt++) {
      int colg = col0 + wcol + nt * 16 + l16;
      float bv_ = BIAS ? bias[colg] : 0.f;
      float v4[4];
#pragma unroll
      for (int r = 0; r < 4; r++) {
        float v = acc[mt][nt][r] + bv_;
        if (GELU) v = 0.5f * v * (1.0f + erff(v * 0.70710678118654752f));
        v4[r] = v;
      }
      int rowg0 = row0 + wrow + mt * 16 + quad * 4;
      if (OUTMODE == 2) {
        ushort4 o;
        o.x = f2b(v4[0]); o.y = f2b(v4[1]); o.z = f2b(v4[2]); o.w = f2b(v4[3]);
        *(ushort4*)((ushort*)C + (size_t)colg * M + rowg0) = o;
      } else {
#pragma unroll
        for (int r = 0; r < 4; r++) {
          if (OUTMODE == 1)
            ((ushort*)C)[(size_t)(rowg0 + r) * N + colg] = f2b(v4[r]);
          else
            ((float*)C)[(size_t)(rowg0 + r) * N + colg] = v4[r];
        }
      }
    }
  }
}

// ---------------------------------------------------------------------------
// MFMA flash attention. Q,K: bf16 (B*M, 768) token-major. Vt: bf16 (768, B*M)
// (dh-major = B^T layout for PV). mask: fp32 (B, M) additive per key.
// Block = (64-query tile, h, b); 4 waves; wave owns 16 query rows.
// Key chunks of 128. Online softmax in registers (C-layout rows = quad*4+r,
// cols = l16 => row reductions are 16-lane shfl_xor). P round-trips through
// LDS (wave-local rows: no barrier needed). O accumulates fp32 in regs.
// LDS: Qs 9216B + Ks 18432B + Vts 17408B + Ps 17408B = 62464B -> 2 blk/CU.
// ---------------------------------------------------------------------------
__global__ __launch_bounds__(256) void attn_mfma_kernel(
    const ushort* __restrict__ Q, const ushort* __restrict__ K,
    const ushort* __restrict__ Vt, const float* __restrict__ mask,
    ushort* __restrict__ O) {
  const int qt = blockIdx.x, h = blockIdx.y, b = blockIdx.z;
  const int tid = threadIdx.x;
  const int lane = tid & 63;
  const int quad = lane >> 4, l16 = lane & 15;
  const int wu = __builtin_amdgcn_readfirstlane(tid >> 6);

  __shared__ __align__(16) ushort Qs[64 * 72];    // stride 72 shorts
  __shared__ __align__(16) ushort Ks[128 * 72];
  __shared__ __align__(16) ushort Vts[64 * 136];  // stride 136 shorts
  __shared__ __align__(16) ushort Ps[64 * 136];

  // ---- stage Q tile (64 x 64)
#pragma unroll
  for (int p = 0; p < 2; p++) {
    int cid = tid + p * 256;
    int j = cid >> 3, g = cid & 7;
    *(short8*)(Qs + j * 72 + g * 8) =
        *(const short8*)(Q + ((size_t)(b * SEQ + qt * 64 + j)) * D_MODEL + h * DHEAD + g * 8);
  }
  __syncthreads();

  short8 qf[2];
#pragma unroll
  for (int kk = 0; kk < 2; kk++)
    qf[kk] = *(const short8*)(Qs + (wu * 16 + l16) * 72 + kk * 32 + quad * 8);

  float m_[4], l_[4];
#pragma unroll
  for (int r = 0; r < 4; r++) { m_[r] = -3.0e38f; l_[r] = 0.f; }
  floatx4 o_acc[4] = {};

  for (int n0 = 0; n0 < SEQ; n0 += 128) {
    __syncthreads();   // protect Ks/Vts (prev chunk readers done)
    // ---- stage K chunk (128 keys x 64)
#pragma unroll
    for (int p = 0; p < 4; p++) {
      int cid = tid + p * 256;
      int j = cid >> 3, g = cid & 7;
      *(short8*)(Ks + j * 72 + g * 8) =
          *(const short8*)(K + ((size_t)(b * SEQ + n0 + j)) * D_MODEL + h * DHEAD + g * 8);
    }
    // ---- stage V^T chunk (64 dh x 128 keys), already transposed in global
#pragma unroll
    for (int p = 0; p < 4; p++) {
      int cid = tid + p * 256;
      int d = cid >> 4, g = cid & 15;
      *(short8*)(Vts + d * 136 + g * 8) =
          *(const short8*)(Vt + ((size_t)(h * DHEAD + d)) * BM + b * SEQ + n0 + g * 8);
    }
    __syncthreads();

    // ---- S = Q @ K^T : 8 col-tiles of 16 keys
    floatx4 sa[8];
#pragma unroll
    for (int ct = 0; ct < 8; ct++) {
      floatx4 acc = {};
#pragma unroll
      for (int kk = 0; kk < 2; kk++) {
        short8 bfr = *(const short8*)(Ks + (ct * 16 + l16) * 72 + kk * 32 + quad * 8);
        acc = __builtin_amdgcn_mfma_f32_16x16x32_bf16(qf[kk], bfr, acc, 0, 0, 0);
      }
      sa[ct] = acc;
    }

    float maskv[8];
#pragma unroll
    for (int ct = 0; ct < 8; ct++)
      maskv[ct] = mask[(size_t)b * SEQ + n0 + ct * 16 + l16];

    // ---- online softmax per row (row = quad*4 + r; cols across ct regs + l16 lanes)
#pragma unroll
    for (int r = 0; r < 4; r++) {
      float mx = -3.0e38f;
#pragma unroll
      for (int ct = 0; ct < 8; ct++) {
        float s = sa[ct][r] * 0.125f + maskv[ct];
        sa[ct][r] = s;
        mx = fmaxf(mx, s);
      }
      mx = fmaxf(mx, __shfl_xor(mx, 1));
      mx = fmaxf(mx, __shfl_xor(mx, 2));
      mx = fmaxf(mx, __shfl_xor(mx, 4));
      mx = fmaxf(mx, __shfl_xor(mx, 8));
      float mnew = fmaxf(m_[r], mx);
      float alpha = __expf(m_[r] - mnew);
      m_[r] = mnew;
      float sum = 0.f;
      int prow = (wu * 16 + quad * 4 + r) * 136;
#pragma unroll
      for (int ct = 0; ct < 8; ct++) {
        float p = __expf(sa[ct][r] - mnew);
        sum += p;
        Ps[prow + ct * 16 + l16] = f2b(p);
      }
      sum += __shfl_xor(sum, 1);
      sum += __shfl_xor(sum, 2);
      sum += __shfl_xor(sum, 4);
      sum += __shfl_xor(sum, 8);
      l_[r] = l_[r] * alpha + sum;
#pragma unroll
      for (int t2 = 0; t2 < 4; t2++) o_acc[t2][r] *= alpha;
    }
    __asm__ __volatile__("" ::: "memory");  // keep Ps writes before reads

    // ---- O += P @ V  (A-frags from Ps, wave-local rows; B-frags from Vts)
    short8 pa[4];
#pragma unroll
    for (int kk2 = 0; kk2 < 4; kk2++)
      pa[kk2] = *(const short8*)(Ps + (wu * 16 + l16) * 136 + kk2 * 32 + quad * 8);
#pragma unroll
    for (int t2 = 0; t2 < 4; t2++) {
#pragma unroll
      for (int kk2 = 0; kk2 < 4; kk2++) {
        short8 vb = *(const short8*)(Vts + (t2 * 16 + l16) * 136 + kk2 * 32 + quad * 8);
        o_acc[t2] = __builtin_amdgcn_mfma_f32_16x16x32_bf16(pa[kk2], vb, o_acc[t2], 0, 0, 0);
      }
    }
  }

  // ---- normalize + write bf16 (token-major (B*M, 768))
#pragma unroll
  for (int r = 0; r < 4; r++) {
    float inv = 1.f / l_[r];
    size_t rowg = (size_t)(b * SEQ + qt * 64 + wu * 16 + quad * 4 + r);
#pragma unroll
    for (int t2 = 0; t2 < 4; t2++)
      O[rowg * D_MODEL + h * DHEAD + t2 * 16 + l16] = f2b(o_acc[t2][r] * inv);
  }
}

// ---------------------------------------------------------------------------
// out = LayerNorm(Ain + Bin)*g + bt ; optional bf16 copy outb. 768 cols.
// ---------------------------------------------------------------------------
__global__ __launch_bounds__(256) void add_ln_kernel(
    const float* __restrict__ Ain, const float* __restrict__ Bin,
    const float* __restrict__ g, const float* __restrict__ bt,
    float* __restrict__ out, ushort* __restrict__ outb) {
  const int row = blockIdx.x, tid = threadIdx.x;
  __shared__ float red[4];
  float v[3];
  float s = 0.f;
#pragma unroll
  for (int u = 0; u < 3; u++) {
    int c = tid + u * 256;
    v[u] = Ain[(size_t)row * 768 + c] + Bin[(size_t)row * 768 + c];
    s += v[u];
  }
#pragma unroll
  for (int off = 32; off > 0; off >>= 1) s += __shfl_down(s, off);
  if ((tid & 63) == 0) red[tid >> 6] = s;
  __syncthreads();
  float mu = (red[0] + red[1] + red[2] + red[3]) * (1.f / 768.f);
  float s2 = 0.f;
#pragma unroll
  for (int u = 0; u < 3; u++) { float d = v[u] - mu; s2 += d * d; }
#pragma unroll
  for (int off = 32; off > 0; off >>= 1) s2 += __shfl_down(s2, off);
  __syncthreads();
  if ((tid & 63) == 0) red[tid >> 6] = s2;
  __syncthreads();
  float var = (red[0] + red[1] + red[2] + red[3]) * (1.f / 768.f);
  float inv = rsqrtf(var + 1e-12f);
#pragma unroll
  for (int u = 0; u < 3; u++) {
    int c = tid + u * 256;
    float r = g[c] * (v[u] - mu) * inv + bt[c];
    out[(size_t)row * 768 + c] = r;
    if (outb) outb[(size_t)row * 768 + c] = f2b(r);
  }
}

// ---------------------------------------------------------------------------
extern "C" void kernel_launch(void* const* d_in, const int* in_sizes, int n_in,
                              void* d_out, int out_size, void* d_ws, size_t ws_size,
                              hipStream_t stream) {
  const float* x    = (const float*)d_in[0];
  const float* mask = (const float*)d_in[1];
  const float* Pq   = (const float*)d_in[2];
  const float* Vq   = (const float*)d_in[3];
  const float* bq   = (const float*)d_in[4];
  const float* Pk   = (const float*)d_in[5];
  const float* Vk   = (const float*)d_in[6];
  const float* bk   = (const float*)d_in[7];
  const float* Pv   = (const float*)d_in[8];
  const float* Vv   = (const float*)d_in[9];
  const float* bv   = (const float*)d_in[10];
  const float* Uo   = (const float*)d_in[11];
  const float* Vo   = (const float*)d_in[12];
  const float* bo   = (const float*)d_in[13];
  const float* U1   = (const float*)d_in[14];
  const float* V1   = (const float*)d_in[15];
  const float* b1   = (const float*)d_in[16];
  const float* U2   = (const float*)d_in[17];
  const float* V2   = (const float*)d_in[18];
  const float* b2   = (const float*)d_in[19];
  const float* g1   = (const float*)d_in[20];
  const float* be1  = (const float*)d_in[21];
  const float* g2   = (const float*)d_in[22];
  const float* be2  = (const float*)d_in[23];

  // --- workspace carve (bytes, 256-aligned) ---
  char* w = (char*)d_ws;
  auto alloc = [&](size_t bytes) -> char* {
    char* p = w; w += (bytes + 255) & ~(size_t)255; return p;
  };
  ushort* xb    = (ushort*)alloc((size_t)BM * 768 * 2);
  ushort* Wqt   = (ushort*)alloc(768 * 768 * 2);
  ushort* Wkt   = (ushort*)alloc(768 * 768 * 2);
  ushort* Wvt   = (ushort*)alloc(768 * 768 * 2);
  ushort* Uot   = (ushort*)alloc(384 * 768 * 2);
  ushort* Vot   = (ushort*)alloc(768 * 384 * 2);
  ushort* U1t   = (ushort*)alloc(384 * 768 * 2);
  ushort* V1t   = (ushort*)alloc((size_t)3072 * 384 * 2);
  ushort* U2t   = (ushort*)alloc((size_t)384 * 3072 * 2);
  ushort* V2t   = (ushort*)alloc(768 * 384 * 2);
  ushort* Qb    = (ushort*)alloc((size_t)BM * 768 * 2);   // bf16 token-major
  ushort* Kb    = (ushort*)alloc((size_t)BM * 768 * 2);
  ushort* Vtb   = (ushort*)alloc((size_t)768 * BM * 2);   // bf16 transposed
  ushort* attnb = (ushort*)alloc((size_t)BM * 768 * 2);
  ushort* t1b   = (ushort*)alloc((size_t)BM * 384 * 2);
  float*  y1    = (float*)alloc((size_t)BM * 768 * 4);
  float*  x1    = (float*)alloc((size_t)BM * 768 * 4);
  ushort* x1b   = (ushort*)alloc((size_t)BM * 768 * 2);
  // aliases (dead-buffer reuse)
  ushort* midb    = t1b;            // t1b dead after y1 GEMM
  ushort* hiddenb = Qb;             // Qb+Kb+Vtb+attnb (50.3MB) dead after t1 GEMM
  ushort* t2b     = t1b;            // midb dead after hidden GEMM
  float*  y2      = y1;             // y1 dead after LN1
  float*  outp    = (float*)d_out;

  // 1) conversions / weight prep
  f2b_kernel<<<(BM * 768) / 1024, 256, 0, stream>>>(x, xb, BM * 768);
  combine_w_kernel<<<2304, 256, 0, stream>>>(Pq, Vq, Wqt);
  combine_w_kernel<<<2304, 256, 0, stream>>>(Pk, Vk, Wkt);
  combine_w_kernel<<<2304, 256, 0, stream>>>(Pv, Vv, Wvt);
  transpose_b_kernel<<<dim3(12, 24), 256, 0, stream>>>(Uo, Uot, 768, 384);
  transpose_b_kernel<<<dim3(24, 12), 256, 0, stream>>>(Vo, Vot, 384, 768);
  transpose_b_kernel<<<dim3(12, 24), 256, 0, stream>>>(U1, U1t, 768, 384);
  transpose_b_kernel<<<dim3(96, 12), 256, 0, stream>>>(V1, V1t, 384, 3072);
  transpose_b_kernel<<<dim3(12, 96), 256, 0, stream>>>(U2, U2t, 3072, 384);
  transpose_b_kernel<<<dim3(24, 12), 256, 0, stream>>>(V2, V2t, 384, 768);

  // 2) Q/K/V = x @ W + bias  (bf16 out; V transposed for PV B-operand)
  gemm_mfma_kernel<1, 1, 0><<<dim3(6, 64), 256, 0, stream>>>(xb, Wqt, bq, Qb, BM, 768, 768);
  gemm_mfma_kernel<1, 1, 0><<<dim3(6, 64), 256, 0, stream>>>(xb, Wkt, bk, Kb, BM, 768, 768);
  gemm_mfma_kernel<2, 1, 0><<<dim3(6, 64), 256, 0, stream>>>(xb, Wvt, bv, Vtb, BM, 768, 768);

  // 3) MFMA flash attention -> bf16 (B*M, 768)
  attn_mfma_kernel<<<dim3(16, 12, 8), 256, 0, stream>>>(Qb, Kb, Vtb, mask, attnb);

  // 4) out-projection (low rank) + residual + LN1
  gemm_mfma_kernel<1, 0, 0><<<dim3(3, 64), 256, 0, stream>>>(attnb, Uot, nullptr, t1b, BM, 384, 768);
  gemm_mfma_kernel<0, 1, 0><<<dim3(6, 64), 256, 0, stream>>>(t1b, Vot, bo, y1, BM, 768, 384);
  add_ln_kernel<<<BM, 256, 0, stream>>>(x, y1, g1, be1, x1, x1b);

  // 5) FFN (low rank) with exact GELU
  gemm_mfma_kernel<1, 0, 0><<<dim3(3, 64), 256, 0, stream>>>(x1b, U1t, nullptr, midb, BM, 384, 768);
  gemm_mfma_kernel<1, 1, 1><<<dim3(24, 64), 256, 0, stream>>>(midb, V1t, b1, hiddenb, BM, 3072, 384);
  gemm_mfma_kernel<1, 0, 0><<<dim3(3, 64), 256, 0, stream>>>(hiddenb, U2t, nullptr, t2b, BM, 384, 3072);
  gemm_mfma_kernel<0, 1, 0><<<dim3(6, 64), 256, 0, stream>>>(t2b, V2t, b2, y2, BM, 768, 384);

  // 6) residual + LN2 -> output (fp32)
  add_ln_kernel<<<BM, 256, 0, stream>>>(x1, y2, g2, be2, outp, nullptr);
}

// Round 4
// 506.628 us; speedup vs baseline: 5.3972x; 1.0952x over previous
//
#include <hip/hip_runtime.h>
#include <cstddef>

// Problem constants
#define D_MODEL 768
#define NHEAD   12
#define DHEAD   64
#define RANK    32
#define SEQ     1024
#define BATCH   8
#define BM      8192      // BATCH*SEQ

typedef __attribute__((ext_vector_type(8))) short short8;
typedef __attribute__((ext_vector_type(4))) float floatx4;

__device__ inline ushort f2b(float f) {           // fp32 -> bf16 RNE
  union { float f; unsigned u; } v; v.f = f;
  unsigned r = v.u + 0x7fffu + ((v.u >> 16) & 1u);
  return (ushort)(r >> 16);
}
__device__ inline float b2f(ushort h) {
  union { unsigned u; float f; } v; v.u = ((unsigned)h) << 16;
  return v.f;
}

// ---------------------------------------------------------------------------
__global__ __launch_bounds__(256) void f2b_kernel(
    const float* __restrict__ in, ushort* __restrict__ out, int n) {
  int i = (blockIdx.x * 256 + threadIdx.x) * 4;
  if (i >= n) return;
  float4 v = *(const float4*)(in + i);
  ushort4 o;
  o.x = f2b(v.x); o.y = f2b(v.y); o.z = f2b(v.z); o.w = f2b(v.w);
  *(ushort4*)(out + i) = o;
}

// ---------------------------------------------------------------------------
// Combine per-head low-rank factors, TRANSPOSED bf16 out:
// Wt[c=h*64+k][d] = sum_r P[h,d,r] * Vw[h,r,k]
// ---------------------------------------------------------------------------
__global__ __launch_bounds__(256) void combine_w_kernel(
    const float* __restrict__ P, const float* __restrict__ Vw,
    ushort* __restrict__ Wt) {
  int idx = blockIdx.x * 256 + threadIdx.x;
  if (idx >= D_MODEL * NHEAD * DHEAD) return;
  int c = idx / D_MODEL;
  int d = idx - c * D_MODEL;
  int h = c >> 6, k = c & 63;
  const float* p = P + ((size_t)h * D_MODEL + d) * RANK;
  const float* v = Vw + (size_t)h * RANK * DHEAD + k;
  float s = 0.f;
#pragma unroll
  for (int r = 0; r < RANK; r++) s += p[r] * v[(size_t)r * DHEAD];
  Wt[(size_t)c * D_MODEL + d] = f2b(s);
}

__global__ __launch_bounds__(256) void concat_bias_kernel(
    const float* __restrict__ bq, const float* __restrict__ bk,
    const float* __restrict__ bv, float* __restrict__ out) {
  int i = blockIdx.x * 256 + threadIdx.x;
  if (i >= 2304) return;
  out[i] = (i < 768) ? bq[i] : (i < 1536 ? bk[i - 768] : bv[i - 1536]);
}

// ---------------------------------------------------------------------------
// Transpose + convert: in (R,C) fp32 -> out (C,R) bf16.  R,C % 32 == 0.
// ---------------------------------------------------------------------------
__global__ __launch_bounds__(256) void transpose_b_kernel(
    const float* __restrict__ in, ushort* __restrict__ out, int R, int C) {
  __shared__ float t[32][33];
  int c0 = blockIdx.x * 32, r0 = blockIdx.y * 32;
  int lx = threadIdx.x & 31, ly = threadIdx.x >> 5;
#pragma unroll
  for (int i = 0; i < 32; i += 8)
    t[ly + i][lx] = in[(size_t)(r0 + ly + i) * C + c0 + lx];
  __syncthreads();
#pragma unroll
  for (int i = 0; i < 32; i += 8)
    out[(size_t)(c0 + ly + i) * R + r0 + lx] = f2b(t[lx][ly + i]);
}

// ---------------------------------------------------------------------------
// bf16 MFMA GEMM: C = A[M,K] @ Bt[N,K]^T (+bias) (+gelu)
// OUTMODE: 0 fp32 (M,N); 1 bf16 (M,N); 2 bf16 transposed (N,M);
//          3 fused QKV: cols [0,768)->C (Q, token-major), [768,1536)->C2 (K),
//            [1536,2304)->C3 (V transposed (768, BM))
// ---------------------------------------------------------------------------
template <int OUTMODE, int BIAS, int GELU>
__global__ __launch_bounds__(256) void gemm_mfma_kernel(
    const ushort* __restrict__ A, const ushort* __restrict__ Bt,
    const float* __restrict__ bias, void* __restrict__ C,
    void* __restrict__ C2, void* __restrict__ C3,
    int M, int N, int K) {
  __shared__ __align__(16) ushort Als[128 * 32];
  __shared__ __align__(16) ushort Bls[128 * 32];
  const int tid  = threadIdx.x;
  const int lane = tid & 63;
  const int quad = lane >> 4, l16 = lane & 15;
  const int wu   = __builtin_amdgcn_readfirstlane(tid >> 6);
  const int wrow = (wu >> 1) * 64, wcol = (wu & 1) * 64;
  const int row0 = blockIdx.y * 128, col0 = blockIdx.x * 128;

  floatx4 acc[4][4] = {};

  for (int k0 = 0; k0 < K; k0 += 32) {
    __syncthreads();
#pragma unroll
    for (int is = 0; is < 2; is++) {
      int c = is * 256 + wu * 64 + lane;
      int m = c >> 2, kk = (c & 3) << 3;
      const ushort* ga = A + (size_t)(row0 + m) * K + (k0 + kk);
      ushort* la = Als + (size_t)(is * 256 + wu * 64) * 8;
      __builtin_amdgcn_global_load_lds(
          (const __attribute__((address_space(1))) void*)ga,
          (__attribute__((address_space(3))) void*)la, 16, 0, 0);
      const ushort* gb = Bt + (size_t)(col0 + m) * K + (k0 + kk);
      ushort* lb = Bls + (size_t)(is * 256 + wu * 64) * 8;
      __builtin_amdgcn_global_load_lds(
          (const __attribute__((address_space(1))) void*)gb,
          (__attribute__((address_space(3))) void*)lb, 16, 0, 0);
    }
    __syncthreads();

    short8 af[4], bf[4];
#pragma unroll
    for (int mt = 0; mt < 4; mt++)
      af[mt] = *(const short8*)(Als + ((wrow + mt * 16 + l16) * 32 + quad * 8));
#pragma unroll
    for (int nt = 0; nt < 4; nt++)
      bf[nt] = *(const short8*)(Bls + ((wcol + nt * 16 + l16) * 32 + quad * 8));
#pragma unroll
    for (int mt = 0; mt < 4; mt++)
#pragma unroll
      for (int nt = 0; nt < 4; nt++)
        acc[mt][nt] = __builtin_amdgcn_mfma_f32_16x16x32_bf16(
            af[mt], bf[nt], acc[mt][nt], 0, 0, 0);
  }

  // Epilogue: C/D layout col = lane&15, row = quad*4 + reg
#pragma unroll
  for (int mt = 0; mt < 4; mt++) {
#pragma unroll
    for (int nt = 0; nt < 4; nt++) {
      int colg = col0 + wcol + nt * 16 + l16;
      float bv_ = BIAS ? bias[colg] : 0.f;
      float v4[4];
#pragma unroll
      for (int r = 0; r < 4; r++) {
        float v = acc[mt][nt][r] + bv_;
        if (GELU) v = 0.5f * v * (1.0f + erff(v * 0.70710678118654752f));
        v4[r] = v;
      }
      int rowg0 = row0 + wrow + mt * 16 + quad * 4;
      if (OUTMODE == 2) {
        ushort4 o;
        o.x = f2b(v4[0]); o.y = f2b(v4[1]); o.z = f2b(v4[2]); o.w = f2b(v4[3]);
        *(ushort4*)((ushort*)C + (size_t)colg * M + rowg0) = o;
      } else if (OUTMODE == 3) {
        int seg = col0 / 768;           // block's 128 cols lie in one segment
        int cl = colg - seg * 768;
        if (seg == 2) {
          ushort4 o;
          o.x = f2b(v4[0]); o.y = f2b(v4[1]); o.z = f2b(v4[2]); o.w = f2b(v4[3]);
          *(ushort4*)((ushort*)C3 + (size_t)cl * BM + rowg0) = o;
        } else {
          ushort* dst = (seg == 0) ? (ushort*)C : (ushort*)C2;
#pragma unroll
          for (int r = 0; r < 4; r++)
            dst[(size_t)(rowg0 + r) * D_MODEL + cl] = f2b(v4[r]);
        }
      } else {
#pragma unroll
        for (int r = 0; r < 4; r++) {
          if (OUTMODE == 1)
            ((ushort*)C)[(size_t)(rowg0 + r) * N + colg] = f2b(v4[r]);
          else
            ((float*)C)[(size_t)(rowg0 + r) * N + colg] = v4[r];
        }
      }
    }
  }
}

// ---------------------------------------------------------------------------
// Split-K bf16 MFMA GEMM: Cpart[z] = A[:, z*Kper:(z+1)*Kper] @ Bt^T (fp32)
// grid.z = splits; Ktot = lda; no bias/gelu.
// ---------------------------------------------------------------------------
__global__ __launch_bounds__(256) void gemm_mfma_splitk_kernel(
    const ushort* __restrict__ A, const ushort* __restrict__ Bt,
    float* __restrict__ Cpart, int M, int N, int Ktot, int Kper) {
  __shared__ __align__(16) ushort Als[128 * 32];
  __shared__ __align__(16) ushort Bls[128 * 32];
  const int tid  = threadIdx.x;
  const int lane = tid & 63;
  const int quad = lane >> 4, l16 = lane & 15;
  const int wu   = __builtin_amdgcn_readfirstlane(tid >> 6);
  const int wrow = (wu >> 1) * 64, wcol = (wu & 1) * 64;
  const int row0 = blockIdx.y * 128, col0 = blockIdx.x * 128;
  const int kbase = blockIdx.z * Kper;
  float* Cz = Cpart + (size_t)blockIdx.z * M * N;

  floatx4 acc[4][4] = {};

  for (int k0 = kbase; k0 < kbase + Kper; k0 += 32) {
    __syncthreads();
#pragma unroll
    for (int is = 0; is < 2; is++) {
      int c = is * 256 + wu * 64 + lane;
      int m = c >> 2, kk = (c & 3) << 3;
      const ushort* ga = A + (size_t)(row0 + m) * Ktot + (k0 + kk);
      ushort* la = Als + (size_t)(is * 256 + wu * 64) * 8;
      __builtin_amdgcn_global_load_lds(
          (const __attribute__((address_space(1))) void*)ga,
          (__attribute__((address_space(3))) void*)la, 16, 0, 0);
      const ushort* gb = Bt + (size_t)(col0 + m) * Ktot + (k0 + kk);
      ushort* lb = Bls + (size_t)(is * 256 + wu * 64) * 8;
      __builtin_amdgcn_global_load_lds(
          (const __attribute__((address_space(1))) void*)gb,
          (__attribute__((address_space(3))) void*)lb, 16, 0, 0);
    }
    __syncthreads();

    short8 af[4], bf[4];
#pragma unroll
    for (int mt = 0; mt < 4; mt++)
      af[mt] = *(const short8*)(Als + ((wrow + mt * 16 + l16) * 32 + quad * 8));
#pragma unroll
    for (int nt = 0; nt < 4; nt++)
      bf[nt] = *(const short8*)(Bls + ((wcol + nt * 16 + l16) * 32 + quad * 8));
#pragma unroll
    for (int mt = 0; mt < 4; mt++)
#pragma unroll
      for (int nt = 0; nt < 4; nt++)
        acc[mt][nt] = __builtin_amdgcn_mfma_f32_16x16x32_bf16(
            af[mt], bf[nt], acc[mt][nt], 0, 0, 0);
  }

#pragma unroll
  for (int mt = 0; mt < 4; mt++)
#pragma unroll
    for (int nt = 0; nt < 4; nt++) {
      int colg = col0 + wcol + nt * 16 + l16;
      int rowg0 = row0 + wrow + mt * 16 + quad * 4;
#pragma unroll
      for (int r = 0; r < 4; r++)
        Cz[(size_t)(rowg0 + r) * N + colg] = acc[mt][nt][r];
    }
}

__global__ __launch_bounds__(256) void reduce_splitk_kernel(
    const float* __restrict__ part, ushort* __restrict__ out, int n, int S) {
  int i = (blockIdx.x * 256 + threadIdx.x) * 4;
  if (i >= n) return;
  float4 a = *(const float4*)(part + i);
  for (int s = 1; s < S; s++) {
    float4 b = *(const float4*)(part + (size_t)s * n + i);
    a.x += b.x; a.y += b.y; a.z += b.z; a.w += b.w;
  }
  ushort4 o;
  o.x = f2b(a.x); o.y = f2b(a.y); o.z = f2b(a.z); o.w = f2b(a.w);
  *(ushort4*)(out + i) = o;
}

// ---------------------------------------------------------------------------
// MFMA flash attention v2. Q,K bf16 (B*M,768) token-major; Vt bf16 (768,B*M).
// Block = 128-query tile x (h,b); 4 waves; wave owns 32 rows (2 x 16-row tiles).
// Key chunks of 128. No max-tracking (scores tiny: |S*scale| << 1); l-sum
// deferred to the end. P -> LDS (wave-private rows) -> A-frags for PV.
// LDS: Ks 18432 + Vts 17408 + Ps 34816 = 70656 B -> 2 blocks/CU.
// ---------------------------------------------------------------------------
__global__ __launch_bounds__(256) void attn_mfma_kernel(
    const ushort* __restrict__ Q, const ushort* __restrict__ K,
    const ushort* __restrict__ Vt, const float* __restrict__ mask,
    ushort* __restrict__ O) {
  const int qt = blockIdx.x, h = blockIdx.y, b = blockIdx.z;
  const int tid = threadIdx.x;
  const int lane = tid & 63;
  const int quad = lane >> 4, l16 = lane & 15;
  const int wu = __builtin_amdgcn_readfirstlane(tid >> 6);

  __shared__ __align__(16) ushort Ks[128 * 72];
  __shared__ __align__(16) ushort Vts[64 * 136];
  __shared__ __align__(16) ushort Ps[128 * 136];

  // Q fragments straight from global (read once per block)
  short8 qf[2][2];
#pragma unroll
  for (int rt = 0; rt < 2; rt++) {
    size_t row = (size_t)(b * SEQ + qt * 128 + wu * 32 + rt * 16 + l16);
#pragma unroll
    for (int kk = 0; kk < 2; kk++)
      qf[rt][kk] = *(const short8*)(Q + row * D_MODEL + h * DHEAD + kk * 32 + quad * 8);
  }

  float l_[2][4] = {};
  floatx4 o_acc[2][4] = {};

  for (int n0 = 0; n0 < SEQ; n0 += 128) {
    __syncthreads();   // prev-chunk readers done before overwrite
#pragma unroll
    for (int p = 0; p < 4; p++) {
      int cid = tid + p * 256;
      int j = cid >> 3, g = cid & 7;
      *(short8*)(Ks + j * 72 + g * 8) =
          *(const short8*)(K + ((size_t)(b * SEQ + n0 + j)) * D_MODEL + h * DHEAD + g * 8);
    }
#pragma unroll
    for (int p = 0; p < 4; p++) {
      int cid = tid + p * 256;
      int d = cid >> 4, g = cid & 15;
      *(short8*)(Vts + d * 136 + g * 8) =
          *(const short8*)(Vt + ((size_t)(h * DHEAD + d)) * BM + b * SEQ + n0 + g * 8);
    }
    __syncthreads();

    float maskv[8];
#pragma unroll
    for (int ct = 0; ct < 8; ct++)
      maskv[ct] = mask[(size_t)b * SEQ + n0 + ct * 16 + l16];

    // ---- S = Q @ K^T: K-frags loaded once, reused by both row-tiles
    floatx4 sa[2][8];
#pragma unroll
    for (int ct = 0; ct < 8; ct++) {
      short8 b0 = *(const short8*)(Ks + (ct * 16 + l16) * 72 + quad * 8);
      short8 b1 = *(const short8*)(Ks + (ct * 16 + l16) * 72 + 32 + quad * 8);
#pragma unroll
      for (int rt = 0; rt < 2; rt++) {
        floatx4 acc = {};
        acc = __builtin_amdgcn_mfma_f32_16x16x32_bf16(qf[rt][0], b0, acc, 0, 0, 0);
        acc = __builtin_amdgcn_mfma_f32_16x16x32_bf16(qf[rt][1], b1, acc, 0, 0, 0);
        sa[rt][ct] = acc;
      }
    }

    // ---- softmax numerator (no max shift needed; scores are small) ----
#pragma unroll
    for (int rt = 0; rt < 2; rt++) {
#pragma unroll
      for (int r = 0; r < 4; r++) {
        int prow = (wu * 32 + rt * 16 + quad * 4 + r) * 136;
        float sum = 0.f;
#pragma unroll
        for (int ct = 0; ct < 8; ct++) {
          float p = __expf(sa[rt][ct][r] * 0.125f + maskv[ct]);
          Ps[prow + ct * 16 + l16] = f2b(p);
          sum += p;
        }
        l_[rt][r] += sum;   // per-lane partial; reduced after the loop
      }
    }
    __asm__ __volatile__("" ::: "memory");  // order Ps writes before reads

    // ---- O += P @ V ----
    short8 pa[2][4];
#pragma unroll
    for (int rt = 0; rt < 2; rt++)
#pragma unroll
      for (int kk2 = 0; kk2 < 4; kk2++)
        pa[rt][kk2] = *(const short8*)(Ps + (wu * 32 + rt * 16 + l16) * 136 + kk2 * 32 + quad * 8);
#pragma unroll
    for (int t2 = 0; t2 < 4; t2++) {
#pragma unroll
      for (int kk2 = 0; kk2 < 4; kk2++) {
        short8 vb = *(const short8*)(Vts + (t2 * 16 + l16) * 136 + kk2 * 32 + quad * 8);
#pragma unroll
        for (int rt = 0; rt < 2; rt++)
          o_acc[rt][t2] = __builtin_amdgcn_mfma_f32_16x16x32_bf16(pa[rt][kk2], vb, o_acc[rt][t2], 0, 0, 0);
      }
    }
  }

  // ---- final l reduction + normalize + write bf16 token-major ----
#pragma unroll
  for (int rt = 0; rt < 2; rt++) {
#pragma unroll
    for (int r = 0; r < 4; r++) {
      float l = l_[rt][r];
      l += __shfl_xor(l, 1);
      l += __shfl_xor(l, 2);
      l += __shfl_xor(l, 4);
      l += __shfl_xor(l, 8);
      float inv = 1.f / l;
      size_t rowg = (size_t)(b * SEQ + qt * 128 + wu * 32 + rt * 16 + quad * 4 + r);
#pragma unroll
      for (int t2 = 0; t2 < 4; t2++)
        O[rowg * D_MODEL + h * DHEAD + t2 * 16 + l16] = f2b(o_acc[rt][t2][r] * inv);
    }
  }
}

// ---------------------------------------------------------------------------
// out = LayerNorm(Ain + Bin)*g + bt. Bin bf16. Ain fp32 or bf16.
// OUT_FP32 -> outf; OUT_BF16 -> outb. 768 cols, eps=1e-12.
// ---------------------------------------------------------------------------
template <int AIN_BF16, int OUT_FP32, int OUT_BF16>
__global__ __launch_bounds__(256) void add_ln_kernel(
    const float* __restrict__ Ainf, const ushort* __restrict__ Ainb,
    const ushort* __restrict__ Binb,
    const float* __restrict__ g, const float* __restrict__ bt,
    float* __restrict__ outf, ushort* __restrict__ outb) {
  const int row = blockIdx.x, tid = threadIdx.x;
  __shared__ float red[4];
  float v[3];
  float s = 0.f;
#pragma unroll
  for (int u = 0; u < 3; u++) {
    int c = tid + u * 256;
    float a = AIN_BF16 ? b2f(Ainb[(size_t)row * 768 + c]) : Ainf[(size_t)row * 768 + c];
    v[u] = a + b2f(Binb[(size_t)row * 768 + c]);
    s += v[u];
  }
#pragma unroll
  for (int off = 32; off > 0; off >>= 1) s += __shfl_down(s, off);
  if ((tid & 63) == 0) red[tid >> 6] = s;
  __syncthreads();
  float mu = (red[0] + red[1] + red[2] + red[3]) * (1.f / 768.f);
  float s2 = 0.f;
#pragma unroll
  for (int u = 0; u < 3; u++) { float d = v[u] - mu; s2 += d * d; }
#pragma unroll
  for (int off = 32; off > 0; off >>= 1) s2 += __shfl_down(s2, off);
  __syncthreads();
  if ((tid & 63) == 0) red[tid >> 6] = s2;
  __syncthreads();
  float var = (red[0] + red[1] + red[2] + red[3]) * (1.f / 768.f);
  float inv = rsqrtf(var + 1e-12f);
#pragma unroll
  for (int u = 0; u < 3; u++) {
    int c = tid + u * 256;
    float r = g[c] * (v[u] - mu) * inv + bt[c];
    if (OUT_FP32) outf[(size_t)row * 768 + c] = r;
    if (OUT_BF16) outb[(size_t)row * 768 + c] = f2b(r);
  }
}

// ---------------------------------------------------------------------------
extern "C" void kernel_launch(void* const* d_in, const int* in_sizes, int n_in,
                              void* d_out, int out_size, void* d_ws, size_t ws_size,
                              hipStream_t stream) {
  const float* x    = (const float*)d_in[0];
  const float* mask = (const float*)d_in[1];
  const float* Pq   = (const float*)d_in[2];
  const float* Vq   = (const float*)d_in[3];
  const float* bq   = (const float*)d_in[4];
  const float* Pk   = (const float*)d_in[5];
  const float* Vk   = (const float*)d_in[6];
  const float* bk   = (const float*)d_in[7];
  const float* Pv   = (const float*)d_in[8];
  const float* Vv   = (const float*)d_in[9];
  const float* bv   = (const float*)d_in[10];
  const float* Uo   = (const float*)d_in[11];
  const float* Vo   = (const float*)d_in[12];
  const float* bo   = (const float*)d_in[13];
  const float* U1   = (const float*)d_in[14];
  const float* V1   = (const float*)d_in[15];
  const float* b1   = (const float*)d_in[16];
  const float* U2   = (const float*)d_in[17];
  const float* V2   = (const float*)d_in[18];
  const float* b2   = (const float*)d_in[19];
  const float* g1   = (const float*)d_in[20];
  const float* be1  = (const float*)d_in[21];
  const float* g2   = (const float*)d_in[22];
  const float* be2  = (const float*)d_in[23];

  // --- workspace carve (bytes, 256-aligned) ---
  char* w = (char*)d_ws;
  auto alloc = [&](size_t bytes) -> char* {
    char* p = w; w += (bytes + 255) & ~(size_t)255; return p;
  };
  ushort* xb     = (ushort*)alloc((size_t)BM * 768 * 2);
  ushort* Wqkvt  = (ushort*)alloc((size_t)2304 * 768 * 2);  // [Wq;Wk;Wv] transposed
  float*  ball   = (float*)alloc(2304 * 4);
  ushort* Uot    = (ushort*)alloc(384 * 768 * 2);
  ushort* Vot    = (ushort*)alloc(768 * 384 * 2);
  ushort* U1t    = (ushort*)alloc(384 * 768 * 2);
  ushort* V1t    = (ushort*)alloc((size_t)3072 * 384 * 2);
  ushort* U2t    = (ushort*)alloc((size_t)384 * 3072 * 2);
  ushort* V2t    = (ushort*)alloc(768 * 384 * 2);
  ushort* Qb     = (ushort*)alloc((size_t)BM * 768 * 2);   // contiguous 4-buffer
  ushort* Kb     = (ushort*)alloc((size_t)BM * 768 * 2);   // region reused as
  ushort* Vtb    = (ushort*)alloc((size_t)768 * BM * 2);   // hiddenb (50.3MB)
  ushort* attnb  = (ushort*)alloc((size_t)BM * 768 * 2);
  ushort* t1b    = (ushort*)alloc((size_t)BM * 384 * 2);
  ushort* y1b    = (ushort*)alloc((size_t)BM * 768 * 2);
  ushort* x1b    = (ushort*)alloc((size_t)BM * 768 * 2);
  float*  part   = (float*)alloc((size_t)4 * BM * 384 * 4); // split-K partials
  // aliases (dead-buffer reuse)
  ushort* midb    = t1b;            // t1b dead after y1 GEMM
  ushort* hiddenb = Qb;             // QKV/attn buffers dead after t1 GEMM
  ushort* t2b     = t1b;            // midb dead after hidden GEMM
  ushort* y2b     = y1b;            // y1b dead after LN1
  float*  outp    = (float*)d_out;

  // 1) conversions / weight prep
  f2b_kernel<<<(BM * 768) / 1024, 256, 0, stream>>>(x, xb, BM * 768);
  combine_w_kernel<<<2304, 256, 0, stream>>>(Pq, Vq, Wqkvt);
  combine_w_kernel<<<2304, 256, 0, stream>>>(Pk, Vk, Wqkvt + (size_t)768 * 768);
  combine_w_kernel<<<2304, 256, 0, stream>>>(Pv, Vv, Wqkvt + (size_t)1536 * 768);
  concat_bias_kernel<<<9, 256, 0, stream>>>(bq, bk, bv, ball);
  transpose_b_kernel<<<dim3(12, 24), 256, 0, stream>>>(Uo, Uot, 768, 384);
  transpose_b_kernel<<<dim3(24, 12), 256, 0, stream>>>(Vo, Vot, 384, 768);
  transpose_b_kernel<<<dim3(12, 24), 256, 0, stream>>>(U1, U1t, 768, 384);
  transpose_b_kernel<<<dim3(96, 12), 256, 0, stream>>>(V1, V1t, 384, 3072);
  transpose_b_kernel<<<dim3(12, 96), 256, 0, stream>>>(U2, U2t, 3072, 384);
  transpose_b_kernel<<<dim3(24, 12), 256, 0, stream>>>(V2, V2t, 384, 768);

  // 2) fused QKV = x @ [Wq|Wk|Wv] + bias  (Q,K token-major; V transposed)
  gemm_mfma_kernel<3, 1, 0><<<dim3(18, 64), 256, 0, stream>>>(
      xb, Wqkvt, ball, Qb, Kb, Vtb, BM, 2304, 768);

  // 3) MFMA flash attention -> bf16 (B*M, 768)
  attn_mfma_kernel<<<dim3(8, 12, 8), 256, 0, stream>>>(Qb, Kb, Vtb, mask, attnb);

  // 4) out-projection (low rank) + residual + LN1
  gemm_mfma_kernel<1, 0, 0><<<dim3(3, 64), 256, 0, stream>>>(
      attnb, Uot, nullptr, t1b, nullptr, nullptr, BM, 384, 768);
  gemm_mfma_kernel<1, 1, 0><<<dim3(6, 64), 256, 0, stream>>>(
      t1b, Vot, bo, y1b, nullptr, nullptr, BM, 768, 384);
  add_ln_kernel<0, 0, 1><<<BM, 256, 0, stream>>>(x, nullptr, y1b, g1, be1, nullptr, x1b);

  // 5) FFN (low rank) with exact GELU
  gemm_mfma_kernel<1, 0, 0><<<dim3(3, 64), 256, 0, stream>>>(
      x1b, U1t, nullptr, midb, nullptr, nullptr, BM, 384, 768);
  gemm_mfma_kernel<1, 1, 1><<<dim3(24, 64), 256, 0, stream>>>(
      midb, V1t, b1, hiddenb, nullptr, nullptr, BM, 3072, 384);
  // t2 = hidden @ U2 : K=3072 -> split-K=4 for occupancy
  gemm_mfma_splitk_kernel<<<dim3(3, 64, 4), 256, 0, stream>>>(
      hiddenb, U2t, part, BM, 384, 3072, 768);
  reduce_splitk_kernel<<<(BM * 384) / 1024, 256, 0, stream>>>(part, t2b, BM * 384, 4);
  gemm_mfma_kernel<1, 1, 0><<<dim3(6, 64), 256, 0, stream>>>(
      t2b, V2t, b2, y2b, nullptr, nullptr, BM, 768, 384);

  // 6) residual + LN2 -> output (fp32)
  add_ln_kernel<1, 1, 0><<<BM, 256, 0, stream>>>(nullptr, x1b, y2b, g2, be2, outp, nullptr);
}